// Round 13
// baseline (164.417 us; speedup 1.0000x reference)
//
#include <hip/hip_runtime.h>
#include <hip/hip_bf16.h>

namespace {

constexpr float kAlpha = 0.025f;
constexpr float kC1 = 1.0e-4f;  // (0.01*1)^2
constexpr float kC2 = 9.0e-4f;  // (0.03*1)^2

constexpr int MPS = 66;  // mp row stride (shorts): 132 B; b64 ops, 0-confl
constexpr int HTS = 72;  // hbT col stride (shorts): 144 B, b128 V-loads

typedef __attribute__((ext_vector_type(8))) short short8;
typedef __attribute__((ext_vector_type(4))) float f32x4;

// Lessons r0-r12: occupancy not the lever (r4); same-address atomic -17%
// (r5); 512-thr tiles regress (r7); row-XOR swizzle backfired 4.5x (r11);
// graded = main + ~55us harness floor, cross-session main noise +-8us.
// r13: A-build was wave-skewed (waves 2,3: ~250 VALU repack; waves 0,1:
// ~30) and every barrier waits on the stragglers. Staging now computes all
// 4 maps (x, y, x2+y2, xy) with all 256 threads; A-build becomes pure LDS
// loads. MPS 72->66 keeps total LDS at 40336 B -> 4 blocks/CU exactly.
struct __align__(16) Smem {
  union {
    short mp[4][64 * MPS];   // bf16 maps: x, y, x2+y2, xy (staging only)
    short hbT[4][32 * HTS];  // bf16 H results, transposed [out_col][row]
  };
  short l1T[32 * HTS];  // l1 plane H result (persistent, outside union)
  float red[4];
  // tap tables: entry e[t] = bf16(g[t-31]) for t-31 in [0,32], else 0.
  // gtab[0][s][i] = (e[2i], e[2i+1]); gtab[1][s][i] = (e[2i+1], e[2i+2])
  int gtab[2][5][48];
};

union Frag {
  int i[4];
  int4 i4;
  short8 s8;
};

__device__ __forceinline__ unsigned f2bf(float f) {  // RNE fp32 -> bf16 bits
  unsigned u = __float_as_uint(f);
  return (u + 0x7FFFu + ((u >> 16) & 1u)) >> 16;
}
__device__ __forceinline__ unsigned pk(float a, float b) {  // v_cvt_pk_bf16
  union {
    __hip_bfloat162 h;
    unsigned u;
  } c;
  c.h = __float22bfloat162_rn(make_float2(a, b));
  return c.u;
}
__device__ __forceinline__ float bfl(unsigned u) {
  return __uint_as_float(u << 16);
}
__device__ __forceinline__ float bfh(unsigned u) {
  return __uint_as_float(u & 0xFFFF0000u);
}
__device__ __forceinline__ float frcp(float x) {  // v_rcp_f32, ~1 ulp
  return __builtin_amdgcn_rcpf(x);
}

// W fragment from the parity table: element j of (nt,kt) = g[k-n],
// k = kt*32 + quad*8 + j, n = nt*16 + l16. Start parity is lane-only, so
// per-lane table base is fixed; fragment = 4 consecutive dwords at
// tb[16kt - 8nt + 8 + j] (compiler -> 2x ds_read2_b32). Symmetric for
// A-operand (V pass, nt=mtile) and B-operand (H pass).
__device__ __forceinline__ short8 wbuild2(const int* tb, int nt, int kt) {
  Frag u;
#pragma unroll
  for (int j = 0; j < 4; ++j) u.i[j] = tb[16 * kt - 8 * nt + 8 + j];
  return u.s8;
}

template <bool USE_WS>
__global__ __launch_bounds__(256, 4) void msssim_l1_kernel(
    const float* __restrict__ x, const float* __restrict__ y,
    const float* __restrict__ gm, float* __restrict__ partial,
    float* __restrict__ out) {
  __shared__ Smem sm;
  const int tid = threadIdx.x;
  const int lane = tid & 63;
  const int w = tid >> 6;
  const int quad = lane >> 4;
  const int l16 = lane & 15;
  const f32x4 kZ = {0.f, 0.f, 0.f, 0.f};  // shared zero C-in for MFMA heads

  // corr: fp32/bf16 tap-sum compensation for the l1 conv (sigma 4)
  float corr;
  {
    float traw4 = (lane < 33) ? gm[4 * 1089 + 528 + lane] : 0.f;
    float g = traw4 * rsqrtf(__shfl(traw4, 16, 64));
    float se = g, st = bfl(f2bf(g));
#pragma unroll
    for (int off = 32; off > 0; off >>= 1) {
      se += __shfl_xor(se, off, 64);
      st += __shfl_xor(st, off, 64);
    }
    float r1 = se / st;
    corr = r1 * r1;
  }

  // build dual-parity tap tables (480 dwords; gm is L2-hot)
  {
    int* gt = &sm.gtab[0][0][0];
    for (int q = tid; q < 480; q += 256) {
      int par = q >= 240;
      int rem = par ? q - 240 : q;
      int s = rem / 48;
      int i = rem - s * 48;
      int t0 = 2 * i + par;
      const float* grow = gm + s * 1089 + 528;
      float rsc = rsqrtf(grow[16]);
      int g0 = t0 - 31, g1 = t0 - 30;
      unsigned lo = (g0 >= 0 && g0 <= 32) ? f2bf(grow[g0] * rsc) : 0u;
      unsigned hi = (g1 >= 0 && g1 <= 32) ? f2bf(grow[g1] * rsc) : 0u;
      gt[q] = (int)(lo | (hi << 16));
    }
  }

  // per-lane table base: parity of start = (l16+1)&1; bias -8 keeps all
  // wbuild2 immediate offsets non-negative
  const int D = (quad * 8 - l16 + 31) >> 1;
  const int* gD = &sm.gtab[(l16 & 1) ? 0 : 1][0][0] + D - 8;

  // 64x64 halo patch, zero-padded; ALL FOUR bf16 maps built here so the
  // map VALU (square/product + repack) is spread over 256 threads instead
  // of riding on waves 2,3's A-build critical path.
  const float* xb = x + blockIdx.z * (512 * 512);
  const float* yb = y + blockIdx.z * (512 * 512);
  const int rb = blockIdx.y * 32 - 16;
  const int cb = blockIdx.x * 32 - 16;
  for (int f = tid; f < 1024; f += 256) {
    int pr = f >> 4;
    int pc = (f & 15) << 2;
    int gr = rb + pr, gc = cb + pc;
    float4 vx = make_float4(0.f, 0.f, 0.f, 0.f);
    float4 vy = vx;
    if (gr >= 0 && gr < 512 && gc >= 0 && gc < 512) {
      vx = *(const float4*)(xb + gr * 512 + gc);
      vy = *(const float4*)(yb + gr * 512 + gc);
    }
    const int base = pr * MPS + pc;
    *(int2*)(&sm.mp[0][base]) =
        make_int2((int)pk(vx.x, vx.y), (int)pk(vx.z, vx.w));
    *(int2*)(&sm.mp[1][base]) =
        make_int2((int)pk(vy.x, vy.y), (int)pk(vy.z, vy.w));
    float s0 = fmaf(vx.x, vx.x, vy.x * vy.x);
    float s1 = fmaf(vx.y, vx.y, vy.y * vy.y);
    float s2 = fmaf(vx.z, vx.z, vy.z * vy.z);
    float s3 = fmaf(vx.w, vx.w, vy.w * vy.w);
    *(int2*)(&sm.mp[2][base]) = make_int2((int)pk(s0, s1), (int)pk(s2, s3));
    *(int2*)(&sm.mp[3][base]) =
        make_int2((int)pk(vx.x * vy.x, vx.y * vy.y),
                  (int)pk(vx.z * vy.z, vx.w * vy.w));
  }
  __syncthreads();  // B1: patch + tables ready

  // A-fragments: wave w loads ITS plane directly (pure b64 LDS loads, no
  // repack). dA (|x-y|) still built from x,y planes for own mtile (mt==w).
  Frag A[4][2];
  Frag dA[2];
#pragma unroll
  for (int mt = 0; mt < 4; ++mt) {
    const short* pa = &sm.mp[w][(mt * 16 + l16) * MPS + quad * 8];
    *(int2*)&A[mt][0].i[0] = *(const int2*)(pa);
    *(int2*)&A[mt][0].i[2] = *(const int2*)(pa + 4);
    *(int2*)&A[mt][1].i[0] = *(const int2*)(pa + 32);
    *(int2*)&A[mt][1].i[2] = *(const int2*)(pa + 36);
  }
  {
    const int row = (w * 16 + l16) * MPS + quad * 8;
    const short* px = &sm.mp[0][row];
    const short* py = &sm.mp[1][row];
    Frag fx[2], fy[2];
    *(int2*)&fx[0].i[0] = *(const int2*)(px);
    *(int2*)&fx[0].i[2] = *(const int2*)(px + 4);
    *(int2*)&fx[1].i[0] = *(const int2*)(px + 32);
    *(int2*)&fx[1].i[2] = *(const int2*)(px + 36);
    *(int2*)&fy[0].i[0] = *(const int2*)(py);
    *(int2*)&fy[0].i[2] = *(const int2*)(py + 4);
    *(int2*)&fy[1].i[0] = *(const int2*)(py + 32);
    *(int2*)&fy[1].i[2] = *(const int2*)(py + 36);
#pragma unroll
    for (int h = 0; h < 2; ++h)
#pragma unroll
      for (int i = 0; i < 4; ++i) {
        unsigned ux = (unsigned)fx[h].i[i], uy = (unsigned)fy[h].i[i];
        dA[h].i[i] =
            (int)pk(fabsf(bfl(ux) - bfl(uy)), fabsf(bfh(ux) - bfh(uy)));
      }
  }

  // l1 H-pass HOISTED: uses only dA + gtab (ready since B1); result goes
  // straight to l1T (outside the union, so legal before B2). Wave w owns
  // mtile w of the single l1 plane. dA dies here.
  {
    const int* tb = gD + 4 * 48;
#pragma unroll
    for (int nt = 0; nt < 2; ++nt) {
      short8 w0 = wbuild2(tb, nt, 0);
      short8 w1 = wbuild2(tb, nt, 1);
      f32x4 acc = __builtin_amdgcn_mfma_f32_16x16x32_bf16(dA[0].s8, w0, kZ, 0,
                                                          0, 0);
      acc = __builtin_amdgcn_mfma_f32_16x16x32_bf16(dA[1].s8, w1, acc, 0, 0,
                                                    0);
      *(int2*)(&sm.l1T[(nt * 16 + l16) * HTS + w * 16 + quad * 4]) =
          make_int2((int)pk(acc[0], acc[1]), (int)pk(acc[2], acc[3]));
    }
  }
  __syncthreads();  // B2: all mp reads done -> hbT may overwrite the union

  const int mtv = w >> 1, ntv = w & 1;
  f32x4 Pcs = {1.f, 1.f, 1.f, 1.f};
  f32x4 lumP = {0.f, 0.f, 0.f, 0.f};
  f32x4 l1v = {0.f, 0.f, 0.f, 0.f};

  // ============== one sigma per barrier pair: 4 planes in hbT ==============
#pragma unroll
  for (int s = 0; s < 5; ++s) {
    const int* tb = gD + s * 48;
    // H pass: wave w computes map w -> hbT plane w. nt-outer so only 2 W
    // fragments (8 regs) are live at a time.
#pragma unroll
    for (int nt = 0; nt < 2; ++nt) {
      short8 w0 = wbuild2(tb, nt, 0);
      short8 w1 = wbuild2(tb, nt, 1);
#pragma unroll
      for (int mt = 0; mt < 4; ++mt) {
        f32x4 acc = __builtin_amdgcn_mfma_f32_16x16x32_bf16(A[mt][0].s8, w0,
                                                            kZ, 0, 0, 0);
        acc = __builtin_amdgcn_mfma_f32_16x16x32_bf16(A[mt][1].s8, w1, acc, 0,
                                                      0, 0);
        *(int2*)(&sm.hbT[w][(nt * 16 + l16) * HTS + mt * 16 + quad * 4]) =
            make_int2((int)pk(acc[0], acc[1]), (int)pk(acc[2], acc[3]));
      }
    }
    __syncthreads();  // sigma-s hbT ready

    // V pass + combine (incremental: mux, muy, T instead of va[4])
    short8 wa0 = wbuild2(tb, mtv, 0);
    short8 wa1 = wbuild2(tb, mtv, 1);
    f32x4 mux, muy, T;
#pragma unroll
    for (int m = 0; m < 4; ++m) {
      const short* bp = &sm.hbT[m][(ntv * 16 + l16) * HTS + quad * 8];
      Frag b0, b1;
      b0.i4 = *(const int4*)(bp);       // 16B-aligned (HTS=72)
      b1.i4 = *(const int4*)(bp + 32);  // +64 B
      f32x4 acc =
          __builtin_amdgcn_mfma_f32_16x16x32_bf16(wa0, b0.s8, kZ, 0, 0, 0);
      acc = __builtin_amdgcn_mfma_f32_16x16x32_bf16(wa1, b1.s8, acc, 0, 0, 0);
      if (m == 0) {
        mux = acc;
      } else if (m == 1) {
        muy = acc;
      } else if (m == 2) {
#pragma unroll
        for (int r = 0; r < 4; ++r)
          T[r] = (acc[r] - mux[r] * mux[r]) - muy[r] * muy[r];
      } else {
#pragma unroll
        for (int r = 0; r < 4; ++r) {
          float cs =
              (2.f * (acc[r] - mux[r] * muy[r]) + kC2) * frcp(T[r] + kC2);
          Pcs[r] *= cs;
          if (s == 4)
            lumP[r] = ((2.f * (mux[r] * muy[r]) + kC1) *
                       frcp((mux[r] * mux[r] + muy[r] * muy[r]) + kC1)) *
                      Pcs[r];
        }
      }
    }
    if (s == 4) {  // l1 V-pass merged: l1T written before B2, taps = wa0/wa1
      const short* lp = &sm.l1T[(ntv * 16 + l16) * HTS + quad * 8];
      Frag c0, c1;
      c0.i4 = *(const int4*)(lp);
      c1.i4 = *(const int4*)(lp + 32);
      f32x4 a2 =
          __builtin_amdgcn_mfma_f32_16x16x32_bf16(wa0, c0.s8, kZ, 0, 0, 0);
      a2 = __builtin_amdgcn_mfma_f32_16x16x32_bf16(wa1, c1.s8, a2, 0, 0, 0);
#pragma unroll
      for (int r = 0; r < 4; ++r) l1v[r] = a2[r] * corr;
    }
    __syncthreads();  // V reads done, hbT reusable
  }

  // loss_mix = alpha*(1 - lum*PIcs) + (1-alpha)*gaussian_l1
  float lsum = 0.f;
#pragma unroll
  for (int r = 0; r < 4; ++r)
    lsum += kAlpha * (1.f - lumP[r]) + (1.f - kAlpha) * l1v[r];
#pragma unroll
  for (int off = 32; off > 0; off >>= 1) lsum += __shfl_down(lsum, off, 64);
  if ((tid & 63) == 0) sm.red[tid >> 6] = lsum;
  __syncthreads();
  if (tid == 0) {
    float t = sm.red[0] + sm.red[1] + sm.red[2] + sm.red[3];
    if (USE_WS) {
      // contention-free: one plain store per block; reducer kernel sums.
      partial[blockIdx.x + (blockIdx.y << 4) + (blockIdx.z << 8)] = t;
    } else {
      atomicAdd(out, t * (20.f / (16.f * 512.f * 512.f)));
    }
  }
}

__global__ __launch_bounds__(256) void msssim_reduce_kernel(
    const float* __restrict__ partial, float* __restrict__ out) {
  const int tid = threadIdx.x;
  float s = 0.f;
#pragma unroll
  for (int i = 0; i < 16; ++i) s += partial[tid + (i << 8)];
#pragma unroll
  for (int off = 32; off > 0; off >>= 1) s += __shfl_xor(s, off, 64);
  __shared__ float red[4];
  if ((tid & 63) == 0) red[tid >> 6] = s;
  __syncthreads();
  if (tid == 0)
    out[0] =
        (red[0] + red[1] + red[2] + red[3]) * (20.f / (16.f * 512.f * 512.f));
}

}  // namespace

extern "C" void kernel_launch(void* const* d_in, const int* in_sizes, int n_in,
                              void* d_out, int out_size, void* d_ws,
                              size_t ws_size, hipStream_t stream) {
  (void)in_sizes;
  (void)n_in;
  (void)out_size;
  const float* x = (const float*)d_in[0];
  const float* y = (const float*)d_in[1];
  const float* gm = (const float*)d_in[2];
  float* out = (float*)d_out;
  dim3 grid(16, 16, 16);
  if (d_ws != nullptr && ws_size >= 4096 * sizeof(float)) {
    float* partial = (float*)d_ws;
    msssim_l1_kernel<true>
        <<<grid, dim3(256), 0, stream>>>(x, y, gm, partial, out);
    msssim_reduce_kernel<<<1, dim3(256), 0, stream>>>(partial, out);
  } else {
    hipMemsetAsync(out, 0, sizeof(float), stream);
    msssim_l1_kernel<false>
        <<<grid, dim3(256), 0, stream>>>(x, y, gm, nullptr, out);
  }
}

// Round 14
// 125.680 us; speedup vs baseline: 1.3082x; 1.3082x over previous
//
#include <hip/hip_runtime.h>
#include <hip/hip_bf16.h>

namespace {

constexpr float kAlpha = 0.025f;
constexpr float kC1 = 1.0e-4f;  // (0.01*1)^2
constexpr float kC2 = 9.0e-4f;  // (0.03*1)^2

constexpr int MPS = 72;  // mp row stride (shorts): 144 B, 16B-aligned rows
constexpr int HTS = 72;  // hbT col stride (shorts): 144 B, 16B-aligned

typedef __attribute__((ext_vector_type(8))) short short8;
typedef __attribute__((ext_vector_type(4))) float f32x4;

// FINAL (r14 = exact r12, the best graded config: 126.3us).
// Session ledger: r5 atomic->d_ws partials (-17%); r6 b128/stride-72/kZ;
// r12 l1T-merge (one fewer barrier phase). Falsified levers: occupancy
// (r1/r2/r4), 64x32 tiles/512thr (r7), row-XOR swizzle (r11: 4.5x MORE
// conflicts), staging-fattening rebalance (r13: +38us graded). Measured
// noise: graded +-3us, rocprof main +-8us cross-session; remaining
// counter-visible items (6.5M conflicts ~1-2us) are below that bar.
struct __align__(16) Smem {
  union {
    short mp[2][64 * MPS];   // bf16 pixel maps: x, y (staging only)
    short hbT[4][32 * HTS];  // bf16 H results, transposed [out_col][row]
  };
  short l1T[32 * HTS];  // l1 plane H result (persistent, outside union)
  float red[4];
  // tap tables: entry e[t] = bf16(g[t-31]) for t-31 in [0,32], else 0.
  // gtab[0][s][i] = (e[2i], e[2i+1]); gtab[1][s][i] = (e[2i+1], e[2i+2])
  int gtab[2][5][48];
};

union Frag {
  int i[4];
  int4 i4;
  short8 s8;
};

__device__ __forceinline__ unsigned f2bf(float f) {  // RNE fp32 -> bf16 bits
  unsigned u = __float_as_uint(f);
  return (u + 0x7FFFu + ((u >> 16) & 1u)) >> 16;
}
__device__ __forceinline__ unsigned pk(float a, float b) {  // v_cvt_pk_bf16
  union {
    __hip_bfloat162 h;
    unsigned u;
  } c;
  c.h = __float22bfloat162_rn(make_float2(a, b));
  return c.u;
}
__device__ __forceinline__ float bfl(unsigned u) {
  return __uint_as_float(u << 16);
}
__device__ __forceinline__ float bfh(unsigned u) {
  return __uint_as_float(u & 0xFFFF0000u);
}
__device__ __forceinline__ float frcp(float x) {  // v_rcp_f32, ~1 ulp
  return __builtin_amdgcn_rcpf(x);
}

// W fragment from the parity table: element j of (nt,kt) = g[k-n],
// k = kt*32 + quad*8 + j, n = nt*16 + l16. Start parity is lane-only, so
// per-lane table base is fixed; fragment = 4 consecutive dwords at
// tb[16kt - 8nt + 8 + j] (compiler -> 2x ds_read2_b32). Symmetric for
// A-operand (V pass, nt=mtile) and B-operand (H pass).
__device__ __forceinline__ short8 wbuild2(const int* tb, int nt, int kt) {
  Frag u;
#pragma unroll
  for (int j = 0; j < 4; ++j) u.i[j] = tb[16 * kt - 8 * nt + 8 + j];
  return u.s8;
}

__device__ __forceinline__ void load_xy(const Smem& sm, int row, int quad,
                                        Frag fx[2], Frag fy[2]) {
  const short* px = &sm.mp[0][row * MPS + quad * 8];
  const short* py = &sm.mp[1][row * MPS + quad * 8];
  fx[0].i4 = *(const int4*)(px);       // 16B-aligned (144*row + 16*quad)
  fx[1].i4 = *(const int4*)(px + 32);  // +64 B
  fy[0].i4 = *(const int4*)(py);
  fy[1].i4 = *(const int4*)(py + 32);
}

template <bool USE_WS>
__global__ __launch_bounds__(256, 4) void msssim_l1_kernel(
    const float* __restrict__ x, const float* __restrict__ y,
    const float* __restrict__ gm, float* __restrict__ partial,
    float* __restrict__ out) {
  __shared__ Smem sm;
  const int tid = threadIdx.x;
  const int lane = tid & 63;
  const int w = tid >> 6;
  const int quad = lane >> 4;
  const int l16 = lane & 15;
  const f32x4 kZ = {0.f, 0.f, 0.f, 0.f};  // shared zero C-in for MFMA heads

  // corr: fp32/bf16 tap-sum compensation for the l1 conv (sigma 4)
  float corr;
  {
    float traw4 = (lane < 33) ? gm[4 * 1089 + 528 + lane] : 0.f;
    float g = traw4 * rsqrtf(__shfl(traw4, 16, 64));
    float se = g, st = bfl(f2bf(g));
#pragma unroll
    for (int off = 32; off > 0; off >>= 1) {
      se += __shfl_xor(se, off, 64);
      st += __shfl_xor(st, off, 64);
    }
    float r1 = se / st;
    corr = r1 * r1;
  }

  // build dual-parity tap tables (480 dwords; gm is L2-hot)
  {
    int* gt = &sm.gtab[0][0][0];
    for (int q = tid; q < 480; q += 256) {
      int par = q >= 240;
      int rem = par ? q - 240 : q;
      int s = rem / 48;
      int i = rem - s * 48;
      int t0 = 2 * i + par;
      const float* grow = gm + s * 1089 + 528;
      float rsc = rsqrtf(grow[16]);
      int g0 = t0 - 31, g1 = t0 - 30;
      unsigned lo = (g0 >= 0 && g0 <= 32) ? f2bf(grow[g0] * rsc) : 0u;
      unsigned hi = (g1 >= 0 && g1 <= 32) ? f2bf(grow[g1] * rsc) : 0u;
      gt[q] = (int)(lo | (hi << 16));
    }
  }

  // per-lane table base: parity of start = (l16+1)&1; bias -8 keeps all
  // wbuild2 immediate offsets non-negative
  const int D = (quad * 8 - l16 + 31) >> 1;
  const int* gD = &sm.gtab[(l16 & 1) ? 0 : 1][0][0] + D - 8;

  // 64x64 halo patch, zero-padded; bf16 x/y maps in LDS (mp region)
  const float* xb = x + blockIdx.z * (512 * 512);
  const float* yb = y + blockIdx.z * (512 * 512);
  const int rb = blockIdx.y * 32 - 16;
  const int cb = blockIdx.x * 32 - 16;
  for (int f = tid; f < 1024; f += 256) {
    int pr = f >> 4;
    int pc = (f & 15) << 2;
    int gr = rb + pr, gc = cb + pc;
    float4 vx = make_float4(0.f, 0.f, 0.f, 0.f);
    float4 vy = vx;
    if (gr >= 0 && gr < 512 && gc >= 0 && gc < 512) {
      vx = *(const float4*)(xb + gr * 512 + gc);
      vy = *(const float4*)(yb + gr * 512 + gc);
    }
    const int base = pr * MPS + pc;
    *(int2*)(&sm.mp[0][base]) =
        make_int2((int)pk(vx.x, vx.y), (int)pk(vx.z, vx.w));
    *(int2*)(&sm.mp[1][base]) =
        make_int2((int)pk(vy.x, vy.y), (int)pk(vy.z, vy.w));
  }
  __syncthreads();  // B1: patch + tables ready

  // persistent A-fragments for THIS wave's map (m = w), all 4 row tiles;
  // every wave also builds |x-y| fragments for ITS OWN mtile (mt == w)
  Frag A[4][2];
  Frag dA[2];
#pragma unroll
  for (int mt = 0; mt < 4; ++mt) {
    Frag fx[2], fy[2];
    load_xy(sm, mt * 16 + l16, quad, fx, fy);
    if (mt == w) {  // own-mtile |x-y| fragments (l1 plane, balanced)
#pragma unroll
      for (int h = 0; h < 2; ++h)
#pragma unroll
        for (int i = 0; i < 4; ++i) {
          unsigned ux = (unsigned)fx[h].i[i], uy = (unsigned)fy[h].i[i];
          dA[h].i[i] =
              (int)pk(fabsf(bfl(ux) - bfl(uy)), fabsf(bfh(ux) - bfh(uy)));
        }
    }
    if (w == 0) {
      A[mt][0] = fx[0];
      A[mt][1] = fx[1];
    } else if (w == 1) {
      A[mt][0] = fy[0];
      A[mt][1] = fy[1];
    } else {
#pragma unroll
      for (int h = 0; h < 2; ++h)
#pragma unroll
        for (int i = 0; i < 4; ++i) {
          unsigned ux = (unsigned)fx[h].i[i], uy = (unsigned)fy[h].i[i];
          float xl = bfl(ux), xh = bfh(ux), yl = bfl(uy), yh = bfh(uy);
          A[mt][h].i[i] = (w == 2) ? (int)pk(fmaf(xl, xl, yl * yl),
                                            fmaf(xh, xh, yh * yh))
                                   : (int)pk(xl * yl, xh * yh);
        }
    }
  }

  // l1 H-pass HOISTED: uses only dA + gtab (ready since B1); result goes
  // straight to l1T (outside the union, so legal before B2). Wave w owns
  // mtile w of the single l1 plane. dA dies here.
  {
    const int* tb = gD + 4 * 48;
#pragma unroll
    for (int nt = 0; nt < 2; ++nt) {
      short8 w0 = wbuild2(tb, nt, 0);
      short8 w1 = wbuild2(tb, nt, 1);
      f32x4 acc = __builtin_amdgcn_mfma_f32_16x16x32_bf16(dA[0].s8, w0, kZ, 0,
                                                          0, 0);
      acc = __builtin_amdgcn_mfma_f32_16x16x32_bf16(dA[1].s8, w1, acc, 0, 0,
                                                    0);
      *(int2*)(&sm.l1T[(nt * 16 + l16) * HTS + w * 16 + quad * 4]) =
          make_int2((int)pk(acc[0], acc[1]), (int)pk(acc[2], acc[3]));
    }
  }
  __syncthreads();  // B2: all mp reads done -> hbT may overwrite the union

  const int mtv = w >> 1, ntv = w & 1;
  f32x4 Pcs = {1.f, 1.f, 1.f, 1.f};
  f32x4 lumP = {0.f, 0.f, 0.f, 0.f};
  f32x4 l1v = {0.f, 0.f, 0.f, 0.f};

  // ============== one sigma per barrier pair: 4 planes in hbT ==============
#pragma unroll
  for (int s = 0; s < 5; ++s) {
    const int* tb = gD + s * 48;
    // H pass: wave w computes map w -> hbT plane w. nt-outer so only 2 W
    // fragments (8 regs) are live at a time.
#pragma unroll
    for (int nt = 0; nt < 2; ++nt) {
      short8 w0 = wbuild2(tb, nt, 0);
      short8 w1 = wbuild2(tb, nt, 1);
#pragma unroll
      for (int mt = 0; mt < 4; ++mt) {
        f32x4 acc = __builtin_amdgcn_mfma_f32_16x16x32_bf16(A[mt][0].s8, w0,
                                                            kZ, 0, 0, 0);
        acc = __builtin_amdgcn_mfma_f32_16x16x32_bf16(A[mt][1].s8, w1, acc, 0,
                                                      0, 0);
        *(int2*)(&sm.hbT[w][(nt * 16 + l16) * HTS + mt * 16 + quad * 4]) =
            make_int2((int)pk(acc[0], acc[1]), (int)pk(acc[2], acc[3]));
      }
    }
    __syncthreads();  // sigma-s hbT ready

    // V pass + combine (incremental: mux, muy, T instead of va[4])
    short8 wa0 = wbuild2(tb, mtv, 0);
    short8 wa1 = wbuild2(tb, mtv, 1);
    f32x4 mux, muy, T;
#pragma unroll
    for (int m = 0; m < 4; ++m) {
      const short* bp = &sm.hbT[m][(ntv * 16 + l16) * HTS + quad * 8];
      Frag b0, b1;
      b0.i4 = *(const int4*)(bp);       // 16B-aligned
      b1.i4 = *(const int4*)(bp + 32);  // +64 B
      f32x4 acc =
          __builtin_amdgcn_mfma_f32_16x16x32_bf16(wa0, b0.s8, kZ, 0, 0, 0);
      acc = __builtin_amdgcn_mfma_f32_16x16x32_bf16(wa1, b1.s8, acc, 0, 0, 0);
      if (m == 0) {
        mux = acc;
      } else if (m == 1) {
        muy = acc;
      } else if (m == 2) {
#pragma unroll
        for (int r = 0; r < 4; ++r)
          T[r] = (acc[r] - mux[r] * mux[r]) - muy[r] * muy[r];
      } else {
#pragma unroll
        for (int r = 0; r < 4; ++r) {
          float cs =
              (2.f * (acc[r] - mux[r] * muy[r]) + kC2) * frcp(T[r] + kC2);
          Pcs[r] *= cs;
          if (s == 4)
            lumP[r] = ((2.f * (mux[r] * muy[r]) + kC1) *
                       frcp((mux[r] * mux[r] + muy[r] * muy[r]) + kC1)) *
                      Pcs[r];
        }
      }
    }
    if (s == 4) {  // l1 V-pass merged: l1T written before B2, taps = wa0/wa1
      const short* lp = &sm.l1T[(ntv * 16 + l16) * HTS + quad * 8];
      Frag c0, c1;
      c0.i4 = *(const int4*)(lp);
      c1.i4 = *(const int4*)(lp + 32);
      f32x4 a2 =
          __builtin_amdgcn_mfma_f32_16x16x32_bf16(wa0, c0.s8, kZ, 0, 0, 0);
      a2 = __builtin_amdgcn_mfma_f32_16x16x32_bf16(wa1, c1.s8, a2, 0, 0, 0);
#pragma unroll
      for (int r = 0; r < 4; ++r) l1v[r] = a2[r] * corr;
    }
    __syncthreads();  // V reads done, hbT reusable
  }

  // loss_mix = alpha*(1 - lum*PIcs) + (1-alpha)*gaussian_l1
  float lsum = 0.f;
#pragma unroll
  for (int r = 0; r < 4; ++r)
    lsum += kAlpha * (1.f - lumP[r]) + (1.f - kAlpha) * l1v[r];
#pragma unroll
  for (int off = 32; off > 0; off >>= 1) lsum += __shfl_down(lsum, off, 64);
  if ((tid & 63) == 0) sm.red[tid >> 6] = lsum;
  __syncthreads();
  if (tid == 0) {
    float t = sm.red[0] + sm.red[1] + sm.red[2] + sm.red[3];
    if (USE_WS) {
      // contention-free: one plain store per block; reducer kernel sums.
      partial[blockIdx.x + (blockIdx.y << 4) + (blockIdx.z << 8)] = t;
    } else {
      atomicAdd(out, t * (20.f / (16.f * 512.f * 512.f)));
    }
  }
}

__global__ __launch_bounds__(256) void msssim_reduce_kernel(
    const float* __restrict__ partial, float* __restrict__ out) {
  const int tid = threadIdx.x;
  float s = 0.f;
#pragma unroll
  for (int i = 0; i < 16; ++i) s += partial[tid + (i << 8)];
#pragma unroll
  for (int off = 32; off > 0; off >>= 1) s += __shfl_xor(s, off, 64);
  __shared__ float red[4];
  if ((tid & 63) == 0) red[tid >> 6] = s;
  __syncthreads();
  if (tid == 0)
    out[0] =
        (red[0] + red[1] + red[2] + red[3]) * (20.f / (16.f * 512.f * 512.f));
}

}  // namespace

extern "C" void kernel_launch(void* const* d_in, const int* in_sizes, int n_in,
                              void* d_out, int out_size, void* d_ws,
                              size_t ws_size, hipStream_t stream) {
  (void)in_sizes;
  (void)n_in;
  (void)out_size;
  const float* x = (const float*)d_in[0];
  const float* y = (const float*)d_in[1];
  const float* gm = (const float*)d_in[2];
  float* out = (float*)d_out;
  dim3 grid(16, 16, 16);
  if (d_ws != nullptr && ws_size >= 4096 * sizeof(float)) {
    float* partial = (float*)d_ws;
    msssim_l1_kernel<true>
        <<<grid, dim3(256), 0, stream>>>(x, y, gm, partial, out);
    msssim_reduce_kernel<<<1, dim3(256), 0, stream>>>(partial, out);
  } else {
    hipMemsetAsync(out, 0, sizeof(float), stream);
    msssim_l1_kernel<false>
        <<<grid, dim3(256), 0, stream>>>(x, y, gm, nullptr, out);
  }
}